// Round 15
// baseline (3657.664 us; speedup 1.0000x reference)
//
#include <hip/hip_runtime.h>
#include <hip/hip_fp16.h>

// Bidirectional 2-layer LSTM: B=32, T=1024, IN=256, H=256.
// ws layout: xg  f16 [2][32][1024][1024]        = 134,217,728 B
//            hbt u64 [2][32][2 parity][256]     =     262,144 B (tagged h)
// total = 134,479,872 B
//
// Tag protocol per batch (layer base B): producer at step st stores (B+st+1,h)
// into parity st&1; consumer at step st polls parity (st+1)&1 for tag B+st.
// L0 base=1, L1 base=4096; hbt memset to 0 each launch (replay-safe).
//
// recur13: TWO-BATCH INTERLEAVE to hide the L3 tagged-h round trip (r14 showed
// it's latency-bound: halving traffic gained only 3.5%).
// wg = (d, bp, jq): quarter jq of batches b0=2bp, b1=2bp+1. 512 threads,
// thread = (lb, j, ks): 4 gate-rows x 64-k slice in 128 pinned VGPRs
// (96KB LDS pad -> 1 block/CU -> 2 waves/SIMD -> 256-reg budget, r11 trick).
// Iteration: {dot b0 + DPP-quad gate reduce + ks==0 epilogue  ||  192 pollers
// stage b1.h(st-1)} barrier {dot b1 + epilogue || 192 pollers stage b0.h(st)}
// barrier. Each batch's exchange is in flight during the other's compute.
// Gate reduce = quad_perm xor1+xor2 (pure VALU; r12 proved correctness — its
// regression was ds_swizzle+redundant-VALU, neither present here).
// Deadlock-freedom: induction — all wgs completing iteration st-1 makes every
// iteration-st poll satisfiable (b1 polls need peers' phase-3(st-1) stores;
// b0 polls need peers' phase-1(st) stores, reachable from barrier A).
// Overwrite safety: parity p slot consumed at iteration Y is overwritten at
// Y+2 (b0) / via two barrier generations (b1) — peers provably done reading.

#define T_LEN 1024
#define BATCH 32
#define HID   256
#define G4    1024

struct __align__(16) Half8 { __half h[8]; };

typedef _Float16 f16x2 __attribute__((ext_vector_type(2)));
typedef _Float16 half8_t __attribute__((ext_vector_type(8)));
typedef float f32x4 __attribute__((ext_vector_type(4)));

__device__ __forceinline__ f16x2 pack_f16x2(float lo, float hi) {
    f16x2 r; r.x = (_Float16)lo; r.y = (_Float16)hi; return r;
}
__device__ __forceinline__ float dot2acc(f16x2 a, f16x2 b, float c) {
#if __has_builtin(__builtin_amdgcn_fdot2)
    return __builtin_amdgcn_fdot2(a, b, c, false);
#else
    return c + (float)a.x * (float)b.x + (float)a.y * (float)b.y;
#endif
}

template <int CTRL>
__device__ __forceinline__ float qpermf(float v) {
    int i = __builtin_bit_cast(int, v);
    int r = __builtin_amdgcn_update_dpp(i, i, CTRL, 0xF, 0xF, true);
    return __builtin_bit_cast(float, r);
}

__device__ __forceinline__ float sigm(float x) { return 1.0f / (1.0f + __expf(-x)); }
__device__ __forceinline__ float tanh_fast(float x) {
    float e = __expf(2.f * x);            // inf-safe
    return 1.f - 2.f / (e + 1.f);
}

#define WQ(q, i) __builtin_bit_cast(f16x2, wq[q][i])

// ---- MFMA projection (r13, unchanged): xg = A*W^T + bias, fp16 out ----
__global__ __launch_bounds__(256, 2) void proj_mfma(
    const float* __restrict__ A, int K,
    const float* __restrict__ Wf, const float* __restrict__ Wr,
    const float* __restrict__ bih_f, const float* __restrict__ bhh_f,
    const float* __restrict__ bih_r, const float* __restrict__ bhh_r,
    __half* __restrict__ xg)
{
    const int dir = blockIdx.z;
    const float* __restrict__ W   = dir ? Wr    : Wf;
    const float* __restrict__ bih = dir ? bih_r : bih_f;
    const float* __restrict__ bhh = dir ? bhh_r : bhh_f;
    __half* __restrict__ outp = xg + (size_t)dir * ((size_t)BATCH * T_LEN * G4);

    __shared__ char psm[36864];
    __half* As = (__half*)psm;                // [128][72]
    __half* Bs = (__half*)(psm + 18432);      // [128][72]

    const int tid  = threadIdx.x;
    const int lane = tid & 63;
    const int wave = tid >> 6;
    const int wm   = wave >> 1;
    const int wn   = wave & 1;
    const int fr   = lane & 15;
    const int fk   = lane >> 4;
    const int m0   = blockIdx.y * 128;
    const int n0   = blockIdx.x * 128;

    float biasv[4];
    #pragma unroll
    for (int ni = 0; ni < 4; ++ni) {
        int n = n0 + wn * 64 + ni * 16 + fr;
        biasv[ni] = bih[n] + bhh[n];
    }

    f32x4 acc[4][4];
    #pragma unroll
    for (int mi = 0; mi < 4; ++mi)
        #pragma unroll
        for (int ni = 0; ni < 4; ++ni)
            acc[mi][ni] = (f32x4){0.f, 0.f, 0.f, 0.f};

    for (int k0 = 0; k0 < K; k0 += 64) {
        #pragma unroll
        for (int it = 0; it < 4; ++it) {
            int t2  = tid + it * 256;
            int row = t2 >> 3;
            int ks  = (t2 & 7) * 8;
            const float* pa = &A[(size_t)(m0 + row) * K + k0 + ks];
            const float* pb = &W[(size_t)(n0 + row) * K + k0 + ks];
            float4 a0 = *reinterpret_cast<const float4*>(pa);
            float4 a1 = *reinterpret_cast<const float4*>(pa + 4);
            float4 b0 = *reinterpret_cast<const float4*>(pb);
            float4 b1 = *reinterpret_cast<const float4*>(pb + 4);
            Half8 ha, hb;
            ha.h[0] = __float2half(a0.x); ha.h[1] = __float2half(a0.y);
            ha.h[2] = __float2half(a0.z); ha.h[3] = __float2half(a0.w);
            ha.h[4] = __float2half(a1.x); ha.h[5] = __float2half(a1.y);
            ha.h[6] = __float2half(a1.z); ha.h[7] = __float2half(a1.w);
            hb.h[0] = __float2half(b0.x); hb.h[1] = __float2half(b0.y);
            hb.h[2] = __float2half(b0.z); hb.h[3] = __float2half(b0.w);
            hb.h[4] = __float2half(b1.x); hb.h[5] = __float2half(b1.y);
            hb.h[6] = __float2half(b1.z); hb.h[7] = __float2half(b1.w);
            *reinterpret_cast<Half8*>(&As[row * 72 + ks]) = ha;
            *reinterpret_cast<Half8*>(&Bs[row * 72 + ks]) = hb;
        }
        __syncthreads();

        #pragma unroll
        for (int kk = 0; kk < 2; ++kk) {
            half8_t af[4], bf[4];
            #pragma unroll
            for (int mi = 0; mi < 4; ++mi)
                af[mi] = *reinterpret_cast<const half8_t*>(
                    &As[(wm * 64 + mi * 16 + fr) * 72 + kk * 32 + fk * 8]);
            #pragma unroll
            for (int ni = 0; ni < 4; ++ni)
                bf[ni] = *reinterpret_cast<const half8_t*>(
                    &Bs[(wn * 64 + ni * 16 + fr) * 72 + kk * 32 + fk * 8]);
            #pragma unroll
            for (int mi = 0; mi < 4; ++mi)
                #pragma unroll
                for (int ni = 0; ni < 4; ++ni)
                    acc[mi][ni] = __builtin_amdgcn_mfma_f32_16x16x32_f16(
                        af[mi], bf[ni], acc[mi][ni], 0, 0, 0);
        }
        __syncthreads();
    }

    __half* Cs = (__half*)psm;
    #pragma unroll
    for (int mi = 0; mi < 4; ++mi)
        #pragma unroll
        for (int ni = 0; ni < 4; ++ni) {
            #pragma unroll
            for (int i = 0; i < 4; ++i) {
                int row = wm * 64 + mi * 16 + fk * 4 + i;
                int col = wn * 64 + ni * 16 + fr;
                Cs[row * 136 + col] = __float2half(acc[mi][ni][i] + biasv[ni]);
            }
        }
    __syncthreads();
    #pragma unroll
    for (int it = 0; it < 8; ++it) {
        int slot = it * 256 + tid;
        int row  = slot >> 4;
        int c8   = (slot & 15) * 8;
        Half8 v = *reinterpret_cast<const Half8*>(&Cs[row * 136 + c8]);
        *reinterpret_cast<Half8*>(&outp[(size_t)(m0 + row) * G4 + n0 + c8]) = v;
    }
}

// ---- cooperative recurrence: two-batch interleave ----
// grid 128: bid = jq*32 + d*16 + bp (group (d,bp) members share bid%8 -> XCD).
// hl layout (LDS): [lb][par][slice(=cell>>6)][72 halves] -> slice bases 144B
// apart (bank stagger, 16B aligned). 96KB dynamic LDS forces 1 block/CU.
extern "C" __global__ __launch_bounds__(512, 2) void recur13_kernel(
    const __half* __restrict__ xg,
    const float* __restrict__ Whh_f,           // [1024][256]
    const float* __restrict__ Whh_r,
    float* __restrict__ outp,                  // [32][1024][512]
    unsigned long long* __restrict__ hbt,      // [2][32][2][256] tagged
    unsigned int tagbase)
{
    extern __shared__ char smem[];
    __half* hl = (__half*)smem;   // [(lb*2+par)*4 + slice]*72 + idx

    const int tid = threadIdx.x;
    const int bid = blockIdx.x;
    const int jq  = bid >> 5;
    const int d   = (bid >> 4) & 1;
    const int bp  = bid & 15;
    const float* __restrict__ Whh = d ? Whh_r : Whh_f;

    const int lb = tid >> 8;        // local batch 0/1
    const int u  = tid & 255;
    const int j  = u >> 2;          // cell within quarter
    const int ks = u & 3;           // k-slice (64 k)
    const int b  = bp * 2 + lb;
    const int cell_my = jq * 64 + j;

    // --- one-time: 4 gate-rows x 64-k slice of W_hh -> 128 packed half2 ---
    unsigned wq[4][32];
    #pragma unroll
    for (int q = 0; q < 4; ++q) {
        const float* wrow = Whh + (size_t)((q << 8) + cell_my) * HID + ks * 64;
        #pragma unroll
        for (int i = 0; i < 16; ++i) {
            float4 w4 = *reinterpret_cast<const float4*>(&wrow[i * 4]);
            wq[q][2 * i]     = __builtin_bit_cast(unsigned, pack_f16x2(w4.x, w4.y));
            wq[q][2 * i + 1] = __builtin_bit_cast(unsigned, pack_f16x2(w4.z, w4.w));
        }
    }
    #pragma unroll
    for (int q = 0; q < 4; ++q)
        #pragma unroll
        for (int i = 0; i < 32; ++i)
            asm volatile("" : "+v"(wq[q][i]));   // no remat

    unsigned long long* hb0 = hbt + (size_t)(d * 32 + bp * 2) * 512;
    unsigned long long* hb1 = hb0 + 512;

    // init: own 64 cells/batch: global parity-1 tag=B (h(-1)=0) + hl[.][0]=0
    if (tid < 128) {
        int lbi = tid >> 6;
        int c = jq * 64 + (tid & 63);
        unsigned long long* hbx = lbi ? hb1 : hb0;
        __hip_atomic_store(&hbx[256 + c], (unsigned long long)tagbase << 32,
                           __ATOMIC_RELAXED, __HIP_MEMORY_SCOPE_AGENT);
        hl[((lbi * 2 + 0) * 4 + jq) * 72 + (tid & 63)] = __float2half(0.f);
    }
    // prologue: stage b0 step-0 foreign quarters (parity 1, tag B)
    if (tid < 192) {
        int fq = tid >> 6, qq = fq + (fq >= jq), c = qq * 64 + (tid & 63);
        unsigned long long* src = &hb0[256 + c];
        unsigned long long v = __hip_atomic_load(src, __ATOMIC_RELAXED, __HIP_MEMORY_SCOPE_AGENT);
        while ((unsigned)(v >> 32) != tagbase)
            v = __hip_atomic_load(src, __ATOMIC_RELAXED, __HIP_MEMORY_SCOPE_AGENT);
        hl[((0 * 2 + 0) * 4 + (c >> 6)) * 72 + (c & 63)] =
            __float2half(__uint_as_float((unsigned)v));
    }
    __syncthreads();

    const __half* __restrict__ xgp =
        xg + ((size_t)(d * BATCH + b)) * T_LEN * G4 + ((ks << 8) + cell_my);

    float c_state = 0.f;   // valid in ks==0 lanes

    for (int st = 0; st < T_LEN; ++st) {
        const int t = d ? (T_LEN - 1 - st) : st;
        const int par = st & 1;

        // prefetch xg (needed at end of this thread's dot phase)
        float xv = __half2float(xgp[(size_t)t * G4]);

        // ---- phase 1: compute b0  ||  stage b1.h(st-1) ----
        if (tid < 256) {
            float a0 = 0.f, a1 = 0.f, a2 = 0.f, a3 = 0.f;
            const float4* hp = reinterpret_cast<const float4*>(
                hl + (size_t)((0 * 2 + par) * 4 + ks) * 72);
            #pragma unroll
            for (int i = 0; i < 8; ++i) {
                float4 hv = hp[i];
                f16x2 h0 = __builtin_bit_cast(f16x2, hv.x);
                f16x2 h1 = __builtin_bit_cast(f16x2, hv.y);
                f16x2 h2 = __builtin_bit_cast(f16x2, hv.z);
                f16x2 h3 = __builtin_bit_cast(f16x2, hv.w);
                a0 = dot2acc(h0, WQ(0, 4*i+0), a0); a0 = dot2acc(h1, WQ(0, 4*i+1), a0);
                a0 = dot2acc(h2, WQ(0, 4*i+2), a0); a0 = dot2acc(h3, WQ(0, 4*i+3), a0);
                a1 = dot2acc(h0, WQ(1, 4*i+0), a1); a1 = dot2acc(h1, WQ(1, 4*i+1), a1);
                a1 = dot2acc(h2, WQ(1, 4*i+2), a1); a1 = dot2acc(h3, WQ(1, 4*i+3), a1);
                a2 = dot2acc(h0, WQ(2, 4*i+0), a2); a2 = dot2acc(h1, WQ(2, 4*i+1), a2);
                a2 = dot2acc(h2, WQ(2, 4*i+2), a2); a2 = dot2acc(h3, WQ(2, 4*i+3), a2);
                a3 = dot2acc(h0, WQ(3, 4*i+0), a3); a3 = dot2acc(h1, WQ(3, 4*i+1), a3);
                a3 = dot2acc(h2, WQ(3, 4*i+2), a3); a3 = dot2acc(h3, WQ(3, 4*i+3), a3);
            }
            if      (ks == 0) a0 += xv;
            else if (ks == 1) a1 += xv;
            else if (ks == 2) a2 += xv;
            else              a3 += xv;
            a0 += qpermf<0xB1>(a0); a0 += qpermf<0x4E>(a0);
            a1 += qpermf<0xB1>(a1); a1 += qpermf<0x4E>(a1);
            a2 += qpermf<0xB1>(a2); a2 += qpermf<0x4E>(a2);
            a3 += qpermf<0xB1>(a3); a3 += qpermf<0x4E>(a3);
            if (ks == 0) {
                float ii = sigm(a0), ff = sigm(a1);
                float g2 = tanh_fast(a2), oo = sigm(a3);
                c_state = ff * c_state + ii * g2;
                float h = oo * tanh_fast(c_state);
                unsigned long long pv =
                    ((unsigned long long)(tagbase + (unsigned)st + 1u) << 32) | __float_as_uint(h);
                __hip_atomic_store(&hb0[(size_t)par * 256 + cell_my], pv,
                                   __ATOMIC_RELAXED, __HIP_MEMORY_SCOPE_AGENT);
                hl[((0 * 2 + (par ^ 1)) * 4 + jq) * 72 + j] = __float2half(h);
                outp[((size_t)b * T_LEN + t) * (2 * HID) + d * HID + cell_my] = h;
            }
        } else if (tid < 448) {
            int u2 = tid - 256;
            int fq = u2 >> 6, qq = fq + (fq >= jq), c = qq * 64 + (u2 & 63);
            unsigned long long* src = &hb1[(size_t)(par ^ 1) * 256 + c];
            const unsigned exp = tagbase + (unsigned)st;
            unsigned long long v = __hip_atomic_load(src, __ATOMIC_RELAXED, __HIP_MEMORY_SCOPE_AGENT);
            while ((unsigned)(v >> 32) != exp)
                v = __hip_atomic_load(src, __ATOMIC_RELAXED, __HIP_MEMORY_SCOPE_AGENT);
            hl[((1 * 2 + par) * 4 + (c >> 6)) * 72 + (c & 63)] =
                __float2half(__uint_as_float((unsigned)v));
        }
        __syncthreads();   // C: hl_b1[par] complete; scr-free phases

        // ---- phase 2: compute b1  ||  stage b0.h(st) for next step ----
        if (tid >= 256) {
            float a0 = 0.f, a1 = 0.f, a2 = 0.f, a3 = 0.f;
            const float4* hp = reinterpret_cast<const float4*>(
                hl + (size_t)((1 * 2 + par) * 4 + ks) * 72);
            #pragma unroll
            for (int i = 0; i < 8; ++i) {
                float4 hv = hp[i];
                f16x2 h0 = __builtin_bit_cast(f16x2, hv.x);
                f16x2 h1 = __builtin_bit_cast(f16x2, hv.y);
                f16x2 h2 = __builtin_bit_cast(f16x2, hv.z);
                f16x2 h3 = __builtin_bit_cast(f16x2, hv.w);
                a0 = dot2acc(h0, WQ(0, 4*i+0), a0); a0 = dot2acc(h1, WQ(0, 4*i+1), a0);
                a0 = dot2acc(h2, WQ(0, 4*i+2), a0); a0 = dot2acc(h3, WQ(0, 4*i+3), a0);
                a1 = dot2acc(h0, WQ(1, 4*i+0), a1); a1 = dot2acc(h1, WQ(1, 4*i+1), a1);
                a1 = dot2acc(h2, WQ(1, 4*i+2), a1); a1 = dot2acc(h3, WQ(1, 4*i+3), a1);
                a2 = dot2acc(h0, WQ(2, 4*i+0), a2); a2 = dot2acc(h1, WQ(2, 4*i+1), a2);
                a2 = dot2acc(h2, WQ(2, 4*i+2), a2); a2 = dot2acc(h3, WQ(2, 4*i+3), a2);
                a3 = dot2acc(h0, WQ(3, 4*i+0), a3); a3 = dot2acc(h1, WQ(3, 4*i+1), a3);
                a3 = dot2acc(h2, WQ(3, 4*i+2), a3); a3 = dot2acc(h3, WQ(3, 4*i+3), a3);
            }
            if      (ks == 0) a0 += xv;
            else if (ks == 1) a1 += xv;
            else if (ks == 2) a2 += xv;
            else              a3 += xv;
            a0 += qpermf<0xB1>(a0); a0 += qpermf<0x4E>(a0);
            a1 += qpermf<0xB1>(a1); a1 += qpermf<0x4E>(a1);
            a2 += qpermf<0xB1>(a2); a2 += qpermf<0x4E>(a2);
            a3 += qpermf<0xB1>(a3); a3 += qpermf<0x4E>(a3);
            if (ks == 0) {
                float ii = sigm(a0), ff = sigm(a1);
                float g2 = tanh_fast(a2), oo = sigm(a3);
                c_state = ff * c_state + ii * g2;
                float h = oo * tanh_fast(c_state);
                unsigned long long pv =
                    ((unsigned long long)(tagbase + (unsigned)st + 1u) << 32) | __float_as_uint(h);
                __hip_atomic_store(&hb1[(size_t)par * 256 + cell_my], pv,
                                   __ATOMIC_RELAXED, __HIP_MEMORY_SCOPE_AGENT);
                hl[((1 * 2 + (par ^ 1)) * 4 + jq) * 72 + j] = __float2half(h);
                outp[((size_t)b * T_LEN + t) * (2 * HID) + d * HID + cell_my] = h;
            }
        } else if (tid < 192 && st < T_LEN - 1) {
            int fq = tid >> 6, qq = fq + (fq >= jq), c = qq * 64 + (tid & 63);
            unsigned long long* src = &hb0[(size_t)par * 256 + c];
            const unsigned exp = tagbase + (unsigned)st + 1u;
            unsigned long long v = __hip_atomic_load(src, __ATOMIC_RELAXED, __HIP_MEMORY_SCOPE_AGENT);
            while ((unsigned)(v >> 32) != exp)
                v = __hip_atomic_load(src, __ATOMIC_RELAXED, __HIP_MEMORY_SCOPE_AGENT);
            hl[((0 * 2 + (par ^ 1)) * 4 + (c >> 6)) * 72 + (c & 63)] =
                __float2half(__uint_as_float((unsigned)v));
        }
        __syncthreads();   // A': hl_b0[par^1] complete for next iteration
    }
}

#define RECUR_LDS 98304u

extern "C" void kernel_launch(void* const* d_in, const int* in_sizes, int n_in,
                              void* d_out, int out_size, void* d_ws, size_t ws_size,
                              hipStream_t stream)
{
    const float* x       = (const float*)d_in[0];
    const float* W_ih_f0 = (const float*)d_in[1];
    const float* W_hh_f0 = (const float*)d_in[2];
    const float* b_ih_f0 = (const float*)d_in[3];
    const float* b_hh_f0 = (const float*)d_in[4];
    const float* W_ih_r0 = (const float*)d_in[5];
    const float* W_hh_r0 = (const float*)d_in[6];
    const float* b_ih_r0 = (const float*)d_in[7];
    const float* b_hh_r0 = (const float*)d_in[8];
    const float* W_ih_f1 = (const float*)d_in[9];
    const float* W_hh_f1 = (const float*)d_in[10];
    const float* b_ih_f1 = (const float*)d_in[11];
    const float* b_hh_f1 = (const float*)d_in[12];
    const float* W_ih_r1 = (const float*)d_in[13];
    const float* W_hh_r1 = (const float*)d_in[14];
    const float* b_ih_r1 = (const float*)d_in[15];
    const float* b_hh_r1 = (const float*)d_in[16];

    float* outp = (float*)d_out;

    __half* xg = (__half*)d_ws;
    const size_t xg_bytes = (size_t)2 * BATCH * T_LEN * G4 * sizeof(__half); // 134,217,728
    unsigned long long* hbt = (unsigned long long*)((char*)d_ws + xg_bytes); // 262,144 B

    hipFuncSetAttribute(reinterpret_cast<const void*>(recur13_kernel),
                        hipFuncAttributeMaxDynamicSharedMemorySize, RECUR_LDS);

    // clean tag space every launch (no stale-tag pre-match, fully replay-safe)
    hipMemsetAsync(hbt, 0, 262144, stream);

    // ---- layer 0 ----
    proj_mfma<<<dim3(8, 256, 2), 256, 0, stream>>>(x, 256, W_ih_f0, W_ih_r0,
        b_ih_f0, b_hh_f0, b_ih_r0, b_hh_r0, xg);
    {
        const __half* xg_c = xg;
        unsigned int base0 = 1u;
        void* args[] = {(void*)&xg_c, (void*)&W_hh_f0, (void*)&W_hh_r0,
                        (void*)&outp, (void*)&hbt, (void*)&base0};
        hipLaunchCooperativeKernel(reinterpret_cast<const void*>(recur13_kernel),
                                   dim3(128), dim3(512), args, RECUR_LDS, stream);
    }

    // ---- layer 1 ----
    proj_mfma<<<dim3(8, 256, 2), 256, 0, stream>>>(outp, 512, W_ih_f1, W_ih_r1,
        b_ih_f1, b_hh_f1, b_ih_r1, b_hh_r1, xg);
    {
        const __half* xg_c = xg;
        unsigned int base1 = 4096u;
        void* args[] = {(void*)&xg_c, (void*)&W_hh_f1, (void*)&W_hh_r1,
                        (void*)&outp, (void*)&hbt, (void*)&base1};
        hipLaunchCooperativeKernel(reinterpret_cast<const void*>(recur13_kernel),
                                   dim3(128), dim3(512), args, RECUR_LDS, stream);
    }
}

// Round 16
// 3120.247 us; speedup vs baseline: 1.1722x; 1.1722x over previous
//
#include <hip/hip_runtime.h>
#include <hip/hip_fp16.h>

// Bidirectional 2-layer LSTM: B=32, T=1024, IN=256, H=256.
// ws layout: xg  f16 [2][32][1024][1024]        = 134,217,728 B
//            hbt u64 [2][32][2 parity][256]     =     262,144 B (tagged h)
// total = 134,479,872 B
//
// Tag protocol per (d,b) (layer base B): producer at step st stores (B+st+1,h)
// into parity st&1; consumer at step st polls parity (st+1)&1 for tag B+st.
// L0 base=1, L1 base=4096; hbt memset to 0 each launch (replay-safe).
//
// recur14 = r14 topology (group-of-4 same-XCD, one wg per (d,b,jq)) + r15's
// verified compute layout (thread=(j,ks), 4 gate-rows x 64k in 128 pinned
// VGPRs, quad_perm gate reduce) + early tagged store + ONE barrier/step.
//   roles: tid<256 compute; 256..447 pollers (1 foreign slot each); rest idle.
//   pollers run CONCURRENTLY with compute: poll(st+1) overlaps compute(st)+RT.
// Single-barrier safety: buffers alternate by parity. compute(st) reads buf P;
// poll(st+1)+producers(st) write buf ~P (disjoint cells: foreign vs own).
// poll(st+2) writes buf P only after barrier A(st+1), which compute(st)
// threads reach only after finishing their buf-P reads. Deadlock-free by
// induction over the closed 4-wg group (barrier A(st+1) needs poll(st+1),
// which needs peers' compute(st) stores, reachable from their barrier A(st)).
// h-stage slices use 72-half stride (144B) to stagger banks (r15-verified).

#define T_LEN 1024
#define BATCH 32
#define HID   256
#define G4    1024

struct __align__(16) Half8 { __half h[8]; };

typedef _Float16 f16x2 __attribute__((ext_vector_type(2)));
typedef _Float16 half8_t __attribute__((ext_vector_type(8)));
typedef float f32x4 __attribute__((ext_vector_type(4)));

__device__ __forceinline__ f16x2 pack_f16x2(float lo, float hi) {
    f16x2 r; r.x = (_Float16)lo; r.y = (_Float16)hi; return r;
}
__device__ __forceinline__ float dot2acc(f16x2 a, f16x2 b, float c) {
#if __has_builtin(__builtin_amdgcn_fdot2)
    return __builtin_amdgcn_fdot2(a, b, c, false);
#else
    return c + (float)a.x * (float)b.x + (float)a.y * (float)b.y;
#endif
}

template <int CTRL>
__device__ __forceinline__ float qpermf(float v) {
    int i = __builtin_bit_cast(int, v);
    int r = __builtin_amdgcn_update_dpp(i, i, CTRL, 0xF, 0xF, true);
    return __builtin_bit_cast(float, r);
}

__device__ __forceinline__ float sigm(float x) { return 1.0f / (1.0f + __expf(-x)); }
__device__ __forceinline__ float tanh_fast(float x) {
    float e = __expf(2.f * x);            // inf-safe
    return 1.f - 2.f / (e + 1.f);
}

#define WQ(q, i) __builtin_bit_cast(f16x2, wq[q][i])

// ---- MFMA projection (r13, unchanged): xg = A*W^T + bias, fp16 out ----
__global__ __launch_bounds__(256, 2) void proj_mfma(
    const float* __restrict__ A, int K,
    const float* __restrict__ Wf, const float* __restrict__ Wr,
    const float* __restrict__ bih_f, const float* __restrict__ bhh_f,
    const float* __restrict__ bih_r, const float* __restrict__ bhh_r,
    __half* __restrict__ xg)
{
    const int dir = blockIdx.z;
    const float* __restrict__ W   = dir ? Wr    : Wf;
    const float* __restrict__ bih = dir ? bih_r : bih_f;
    const float* __restrict__ bhh = dir ? bhh_r : bhh_f;
    __half* __restrict__ outp = xg + (size_t)dir * ((size_t)BATCH * T_LEN * G4);

    __shared__ char psm[36864];
    __half* As = (__half*)psm;                // [128][72]
    __half* Bs = (__half*)(psm + 18432);      // [128][72]

    const int tid  = threadIdx.x;
    const int lane = tid & 63;
    const int wave = tid >> 6;
    const int wm   = wave >> 1;
    const int wn   = wave & 1;
    const int fr   = lane & 15;
    const int fk   = lane >> 4;
    const int m0   = blockIdx.y * 128;
    const int n0   = blockIdx.x * 128;

    float biasv[4];
    #pragma unroll
    for (int ni = 0; ni < 4; ++ni) {
        int n = n0 + wn * 64 + ni * 16 + fr;
        biasv[ni] = bih[n] + bhh[n];
    }

    f32x4 acc[4][4];
    #pragma unroll
    for (int mi = 0; mi < 4; ++mi)
        #pragma unroll
        for (int ni = 0; ni < 4; ++ni)
            acc[mi][ni] = (f32x4){0.f, 0.f, 0.f, 0.f};

    for (int k0 = 0; k0 < K; k0 += 64) {
        #pragma unroll
        for (int it = 0; it < 4; ++it) {
            int t2  = tid + it * 256;
            int row = t2 >> 3;
            int ks  = (t2 & 7) * 8;
            const float* pa = &A[(size_t)(m0 + row) * K + k0 + ks];
            const float* pb = &W[(size_t)(n0 + row) * K + k0 + ks];
            float4 a0 = *reinterpret_cast<const float4*>(pa);
            float4 a1 = *reinterpret_cast<const float4*>(pa + 4);
            float4 b0 = *reinterpret_cast<const float4*>(pb);
            float4 b1 = *reinterpret_cast<const float4*>(pb + 4);
            Half8 ha, hb;
            ha.h[0] = __float2half(a0.x); ha.h[1] = __float2half(a0.y);
            ha.h[2] = __float2half(a0.z); ha.h[3] = __float2half(a0.w);
            ha.h[4] = __float2half(a1.x); ha.h[5] = __float2half(a1.y);
            ha.h[6] = __float2half(a1.z); ha.h[7] = __float2half(a1.w);
            hb.h[0] = __float2half(b0.x); hb.h[1] = __float2half(b0.y);
            hb.h[2] = __float2half(b0.z); hb.h[3] = __float2half(b0.w);
            hb.h[4] = __float2half(b1.x); hb.h[5] = __float2half(b1.y);
            hb.h[6] = __float2half(b1.z); hb.h[7] = __float2half(b1.w);
            *reinterpret_cast<Half8*>(&As[row * 72 + ks]) = ha;
            *reinterpret_cast<Half8*>(&Bs[row * 72 + ks]) = hb;
        }
        __syncthreads();

        #pragma unroll
        for (int kk = 0; kk < 2; ++kk) {
            half8_t af[4], bf[4];
            #pragma unroll
            for (int mi = 0; mi < 4; ++mi)
                af[mi] = *reinterpret_cast<const half8_t*>(
                    &As[(wm * 64 + mi * 16 + fr) * 72 + kk * 32 + fk * 8]);
            #pragma unroll
            for (int ni = 0; ni < 4; ++ni)
                bf[ni] = *reinterpret_cast<const half8_t*>(
                    &Bs[(wn * 64 + ni * 16 + fr) * 72 + kk * 32 + fk * 8]);
            #pragma unroll
            for (int mi = 0; mi < 4; ++mi)
                #pragma unroll
                for (int ni = 0; ni < 4; ++ni)
                    acc[mi][ni] = __builtin_amdgcn_mfma_f32_16x16x32_f16(
                        af[mi], bf[ni], acc[mi][ni], 0, 0, 0);
        }
        __syncthreads();
    }

    __half* Cs = (__half*)psm;
    #pragma unroll
    for (int mi = 0; mi < 4; ++mi)
        #pragma unroll
        for (int ni = 0; ni < 4; ++ni) {
            #pragma unroll
            for (int i = 0; i < 4; ++i) {
                int row = wm * 64 + mi * 16 + fk * 4 + i;
                int col = wn * 64 + ni * 16 + fr;
                Cs[row * 136 + col] = __float2half(acc[mi][ni][i] + biasv[ni]);
            }
        }
    __syncthreads();
    #pragma unroll
    for (int it = 0; it < 8; ++it) {
        int slot = it * 256 + tid;
        int row  = slot >> 4;
        int c8   = (slot & 15) * 8;
        Half8 v = *reinterpret_cast<const Half8*>(&Cs[row * 136 + c8]);
        *reinterpret_cast<Half8*>(&outp[(size_t)(m0 + row) * G4 + n0 + c8]) = v;
    }
}

// ---- cooperative recurrence: in-wave DPP epilogue, concurrent pollers ----
// bid = jq*64 + d*32 + b (all 4 jq of (d,b) share bid%8 -> same-XCD heuristic).
// hl: [par][slice ks][72 halves] (144B slice stride, bank-staggered).
extern "C" __global__ __launch_bounds__(512, 2) void recur14_kernel(
    const __half* __restrict__ xg,
    const float* __restrict__ Whh_f,           // [1024][256]
    const float* __restrict__ Whh_r,
    float* __restrict__ outp,                  // [32][1024][512]
    unsigned long long* __restrict__ hbt,      // [2][32][2][256] tagged
    unsigned int tagbase)
{
    extern __shared__ char smem[];             // 96 KB pad -> 1 block/CU
    __half* hl = (__half*)smem;                // [(par*4 + slice)*72 + idx]

    const int tid = threadIdx.x;
    const int bid = blockIdx.x;
    const int jq  = bid >> 6;
    const int d   = (bid >> 5) & 1;
    const int b   = bid & 31;
    const float* __restrict__ Whh = d ? Whh_r : Whh_f;

    const int j  = (tid >> 2) & 63;            // cell within quarter (tid<256)
    const int ks = tid & 3;                    // k-slice
    const int cell_my = jq * 64 + j;

    // --- one-time (compute threads): 4 gate-rows x 64-k -> 128 packed half2 ---
    unsigned wq[4][32];
    if (tid < 256) {
        #pragma unroll
        for (int q = 0; q < 4; ++q) {
            const float* wrow = Whh + (size_t)((q << 8) + cell_my) * HID + ks * 64;
            #pragma unroll
            for (int i = 0; i < 16; ++i) {
                float4 w4 = *reinterpret_cast<const float4*>(&wrow[i * 4]);
                wq[q][2 * i]     = __builtin_bit_cast(unsigned, pack_f16x2(w4.x, w4.y));
                wq[q][2 * i + 1] = __builtin_bit_cast(unsigned, pack_f16x2(w4.z, w4.w));
            }
        }
        #pragma unroll
        for (int q = 0; q < 4; ++q)
            #pragma unroll
            for (int i = 0; i < 32; ++i)
                asm volatile("" : "+v"(wq[q][i]));   // no remat
    }

    unsigned long long* hb = hbt + (size_t)(d * 32 + b) * 512;   // [parity][256]

    // init: h[-1]=0 -> global parity-1 tag (peers) + local hl[0] own slice
    if (tid < 64) {
        __hip_atomic_store(&hb[256 + jq * 64 + tid],
                           (unsigned long long)tagbase << 32,
                           __ATOMIC_RELAXED, __HIP_MEMORY_SCOPE_AGENT);
        hl[(0 * 4 + jq) * 72 + tid] = __float2half(0.f);
    }

    // pollers: tids [256,448), one foreign slot each
    const bool isPoll = (tid >= 256) && (tid < 448);
    int pslot = 0, psl = 0, pof = 0;
    if (isPoll) {
        int u  = tid - 256;            // 0..191
        int fq = u >> 6;               // 0..2
        int qq = fq + (fq >= jq);      // skip own quarter
        pslot  = qq * 64 + (u & 63);
        psl    = pslot >> 6;           // stage slice
        pof    = pslot & 63;
    }

    const __half* __restrict__ xgp =
        xg + ((size_t)(d * BATCH + b)) * T_LEN * G4 + ((ks << 8) + cell_my);

    float c_state = 0.f;   // valid in ks==0 lanes

    for (int st = 0; st < T_LEN; ++st) {
        const int t = d ? (T_LEN - 1 - st) : st;
        const int par = st & 1;

        float xv = 0.f;
        if (tid < 256) xv = __half2float(xgp[(size_t)t * G4]);   // prefetch

        // poll phase: stage foreign h(st-1) (parity (st+1)&1, tag B+st) into hl[par]
        if (isPoll) {
            const unsigned exp = tagbase + (unsigned)st;
            unsigned long long* src = &hb[(size_t)((st + 1) & 1) * 256 + pslot];
            unsigned long long v =
                __hip_atomic_load(src, __ATOMIC_RELAXED, __HIP_MEMORY_SCOPE_AGENT);
            while ((unsigned)(v >> 32) != exp)
                v = __hip_atomic_load(src, __ATOMIC_RELAXED, __HIP_MEMORY_SCOPE_AGENT);
            hl[(par * 4 + psl) * 72 + pof] =
                __float2half(__uint_as_float((unsigned)v));
        }
        __syncthreads();   // barrier A(st): hl[par] complete

        if (tid < 256) {
            float a0 = 0.f, a1 = 0.f, a2 = 0.f, a3 = 0.f;
            const float4* hp = reinterpret_cast<const float4*>(
                hl + (size_t)(par * 4 + ks) * 72);
            #pragma unroll
            for (int i = 0; i < 8; ++i) {
                float4 hv = hp[i];
                f16x2 h0 = __builtin_bit_cast(f16x2, hv.x);
                f16x2 h1 = __builtin_bit_cast(f16x2, hv.y);
                f16x2 h2 = __builtin_bit_cast(f16x2, hv.z);
                f16x2 h3 = __builtin_bit_cast(f16x2, hv.w);
                a0 = dot2acc(h0, WQ(0, 4*i+0), a0); a0 = dot2acc(h1, WQ(0, 4*i+1), a0);
                a0 = dot2acc(h2, WQ(0, 4*i+2), a0); a0 = dot2acc(h3, WQ(0, 4*i+3), a0);
                a1 = dot2acc(h0, WQ(1, 4*i+0), a1); a1 = dot2acc(h1, WQ(1, 4*i+1), a1);
                a1 = dot2acc(h2, WQ(1, 4*i+2), a1); a1 = dot2acc(h3, WQ(1, 4*i+3), a1);
                a2 = dot2acc(h0, WQ(2, 4*i+0), a2); a2 = dot2acc(h1, WQ(2, 4*i+1), a2);
                a2 = dot2acc(h2, WQ(2, 4*i+2), a2); a2 = dot2acc(h3, WQ(2, 4*i+3), a2);
                a3 = dot2acc(h0, WQ(3, 4*i+0), a3); a3 = dot2acc(h1, WQ(3, 4*i+1), a3);
                a3 = dot2acc(h2, WQ(3, 4*i+2), a3); a3 = dot2acc(h3, WQ(3, 4*i+3), a3);
            }
            if      (ks == 0) a0 += xv;
            else if (ks == 1) a1 += xv;
            else if (ks == 2) a2 += xv;
            else              a3 += xv;
            // ks-reduce (xor1 + xor2) via quad_perm DPP (VALU pipe, r15-verified)
            a0 += qpermf<0xB1>(a0); a0 += qpermf<0x4E>(a0);
            a1 += qpermf<0xB1>(a1); a1 += qpermf<0x4E>(a1);
            a2 += qpermf<0xB1>(a2); a2 += qpermf<0x4E>(a2);
            a3 += qpermf<0xB1>(a3); a3 += qpermf<0x4E>(a3);
            if (ks == 0) {
                float ii = sigm(a0), ff = sigm(a1);
                float g2 = tanh_fast(a2), oo = sigm(a3);
                c_state = ff * c_state + ii * g2;
                float h = oo * tanh_fast(c_state);
                // tagged store ASAP (parity st&1, tag B+st+1) — peers' poll gate
                unsigned long long pv =
                    ((unsigned long long)(tagbase + (unsigned)st + 1u) << 32) | __float_as_uint(h);
                __hip_atomic_store(&hb[(size_t)par * 256 + cell_my], pv,
                                   __ATOMIC_RELAXED, __HIP_MEMORY_SCOPE_AGENT);
                // local fast path into hl[(st+1)&1] own slice (jq)
                hl[(((st + 1) & 1) * 4 + jq) * 72 + j] = __float2half(h);
                outp[((size_t)b * T_LEN + t) * (2 * HID) + d * HID + cell_my] = h;
            }
        }
        // no second barrier: poll(st+1) writes hl[par^1] (disjoint from this
        // step's hl[par] reads); poll(st+2)'s hl[par] writes are fenced by
        // barrier A(st+1), which compute threads reach after their reads.
    }
}

#define RECUR_LDS 98304u

extern "C" void kernel_launch(void* const* d_in, const int* in_sizes, int n_in,
                              void* d_out, int out_size, void* d_ws, size_t ws_size,
                              hipStream_t stream)
{
    const float* x       = (const float*)d_in[0];
    const float* W_ih_f0 = (const float*)d_in[1];
    const float* W_hh_f0 = (const float*)d_in[2];
    const float* b_ih_f0 = (const float*)d_in[3];
    const float* b_hh_f0 = (const float*)d_in[4];
    const float* W_ih_r0 = (const float*)d_in[5];
    const float* W_hh_r0 = (const float*)d_in[6];
    const float* b_ih_r0 = (const float*)d_in[7];
    const float* b_hh_r0 = (const float*)d_in[8];
    const float* W_ih_f1 = (const float*)d_in[9];
    const float* W_hh_f1 = (const float*)d_in[10];
    const float* b_ih_f1 = (const float*)d_in[11];
    const float* b_hh_f1 = (const float*)d_in[12];
    const float* W_ih_r1 = (const float*)d_in[13];
    const float* W_hh_r1 = (const float*)d_in[14];
    const float* b_ih_r1 = (const float*)d_in[15];
    const float* b_hh_r1 = (const float*)d_in[16];

    float* outp = (float*)d_out;

    __half* xg = (__half*)d_ws;
    const size_t xg_bytes = (size_t)2 * BATCH * T_LEN * G4 * sizeof(__half); // 134,217,728
    unsigned long long* hbt = (unsigned long long*)((char*)d_ws + xg_bytes); // 262,144 B

    hipFuncSetAttribute(reinterpret_cast<const void*>(recur14_kernel),
                        hipFuncAttributeMaxDynamicSharedMemorySize, RECUR_LDS);

    // clean tag space every launch (no stale-tag pre-match, fully replay-safe)
    hipMemsetAsync(hbt, 0, 262144, stream);

    // ---- layer 0 ----
    proj_mfma<<<dim3(8, 256, 2), 256, 0, stream>>>(x, 256, W_ih_f0, W_ih_r0,
        b_ih_f0, b_hh_f0, b_ih_r0, b_hh_r0, xg);
    {
        const __half* xg_c = xg;
        unsigned int base0 = 1u;
        void* args[] = {(void*)&xg_c, (void*)&W_hh_f0, (void*)&W_hh_r0,
                        (void*)&outp, (void*)&hbt, (void*)&base0};
        hipLaunchCooperativeKernel(reinterpret_cast<const void*>(recur14_kernel),
                                   dim3(256), dim3(512), args, RECUR_LDS, stream);
    }

    // ---- layer 1 ----
    proj_mfma<<<dim3(8, 256, 2), 256, 0, stream>>>(outp, 512, W_ih_f1, W_ih_r1,
        b_ih_f1, b_hh_f1, b_ih_r1, b_hh_r1, xg);
    {
        const __half* xg_c = xg;
        unsigned int base1 = 4096u;
        void* args[] = {(void*)&xg_c, (void*)&W_hh_f1, (void*)&W_hh_r1,
                        (void*)&outp, (void*)&hbt, (void*)&base1};
        hipLaunchCooperativeKernel(reinterpret_cast<const void*>(recur14_kernel),
                                   dim3(256), dim3(512), args, RECUR_LDS, stream);
    }
}